// Round 1
// baseline (78.111 us; speedup 1.0000x reference)
//
#include <hip/hip_runtime.h>

#define BB 2
#define NN 1024
#define MM 1024
#define DIN 16
#define CC 32
#define HH 32

// jax.nn.gelu default (approximate=True): 0.5*v*(1+tanh(sqrt(2/pi)*(v+0.044715 v^3)))
__device__ __forceinline__ float gelu_tanh(float v) {
    float v3 = v * v * v;
    float u = 0.7978845608028654f * (v + 0.044715f * v3);
    float e = __expf(2.0f * u);          // e^(2u); inf/0 at extremes handled below
    float t = 1.0f - 2.0f / (e + 1.0f);  // tanh(u); e=inf -> 1, e=0 -> -1
    return 0.5f * v * (1.0f + t);
}

// Kernel 1: per-batch prep. grid = B blocks, 256 threads.
//  - min/max over N per coord dim, rescale to [-1,1] (bit-exact vs numpy)
//  - a[b,n,h] = xs0*W1[0,h] + xs1*W1[1,h]       (point-side MLP pre-activation)
//  - f[b,n,c] = pndata[b,n,:] @ W_lift + b_lift (lifting)
__global__ __launch_bounds__(256) void gno_prep(
    const float* __restrict__ pndata, const float* __restrict__ x_coord,
    const float* __restrict__ W_lift, const float* __restrict__ b_lift,
    const float* __restrict__ W1,
    float* __restrict__ xs, float* __restrict__ f, float* __restrict__ a)
{
    const int b = blockIdx.x;
    const int t = threadIdx.x;
    __shared__ float WLs[DIN * CC];
    __shared__ float bls[CC];
    __shared__ float red[4 * 4];
    __shared__ float mmx[4];

    for (int idx = t; idx < DIN * CC; idx += 256) WLs[idx] = W_lift[idx];
    if (t < CC) bls[t] = b_lift[t];

    float mn0 = 1e30f, mx0 = -1e30f, mn1 = 1e30f, mx1 = -1e30f;
    for (int n = t; n < NN; n += 256) {
        float2 xy = ((const float2*)x_coord)[b * NN + n];
        mn0 = fminf(mn0, xy.x); mx0 = fmaxf(mx0, xy.x);
        mn1 = fminf(mn1, xy.y); mx1 = fmaxf(mx1, xy.y);
    }
    for (int off = 32; off > 0; off >>= 1) {
        mn0 = fminf(mn0, __shfl_down(mn0, off));
        mx0 = fmaxf(mx0, __shfl_down(mx0, off));
        mn1 = fminf(mn1, __shfl_down(mn1, off));
        mx1 = fmaxf(mx1, __shfl_down(mx1, off));
    }
    const int wave = t >> 6;
    if ((t & 63) == 0) {
        red[wave * 4 + 0] = mn0; red[wave * 4 + 1] = mx0;
        red[wave * 4 + 2] = mn1; red[wave * 4 + 3] = mx1;
    }
    __syncthreads();
    if (t == 0) {
        float a0 = red[0], a1 = red[1], a2 = red[2], a3 = red[3];
        for (int w = 1; w < 4; ++w) {
            a0 = fminf(a0, red[w * 4 + 0]); a1 = fmaxf(a1, red[w * 4 + 1]);
            a2 = fminf(a2, red[w * 4 + 2]); a3 = fmaxf(a3, red[w * 4 + 3]);
        }
        mmx[0] = a0; mmx[1] = a1; mmx[2] = a2; mmx[3] = a3;
    }
    __syncthreads();
    const float Amn0 = mmx[0], Amx0 = mmx[1], Amn1 = mmx[2], Amx1 = mmx[3];
    // denom = (mx - mn) + 1e-12, each op rounded separately (matches numpy)
    const float den0 = __fadd_rn(__fsub_rn(Amx0, Amn0), 1e-12f);
    const float den1 = __fadd_rn(__fsub_rn(Amx1, Amn1), 1e-12f);

    for (int n = t; n < NN; n += 256) {
        float2 xy = ((const float2*)x_coord)[b * NN + n];
        // 2*(x-mn)/den - 1, no contraction
        float r0 = __fsub_rn(__fdiv_rn(__fmul_rn(2.0f, __fsub_rn(xy.x, Amn0)), den0), 1.0f);
        float r1 = __fsub_rn(__fdiv_rn(__fmul_rn(2.0f, __fsub_rn(xy.y, Amn1)), den1), 1.0f);
        xs[(b * NN + n) * 2 + 0] = r0;
        xs[(b * NN + n) * 2 + 1] = r1;
        #pragma unroll
        for (int h = 0; h < HH; ++h)
            a[(b * NN + n) * HH + h] = r0 * W1[h] + r1 * W1[HH + h];
    }

    for (int n = t; n < NN; n += 256) {
        float p[DIN];
        #pragma unroll
        for (int k = 0; k < DIN; ++k) p[k] = pndata[(b * NN + n) * DIN + k];
        #pragma unroll
        for (int c = 0; c < CC; ++c) {
            float acc = bls[c];
            #pragma unroll
            for (int k = 0; k < DIN; ++k) acc = fmaf(p[k], WLs[k * CC + c], acc);
            f[(b * NN + n) * CC + c] = acc;
        }
    }
}

// Kernel 2: one block per (b, query i). 256 threads = 8 groups x 32 channels.
__global__ __launch_bounds__(256) void gno_main(
    const float* __restrict__ latq, const float* __restrict__ W1,
    const float* __restrict__ b1, const float* __restrict__ W2,
    const float* __restrict__ b2,
    const float* __restrict__ xs, const float* __restrict__ f,
    const float* __restrict__ a, float* __restrict__ out)
{
    const int bid = blockIdx.x;
    const int b = bid >> 10;       // M = 1024
    const int i = bid & 1023;
    const int t = threadIdx.x;

    __shared__ float W2s[HH * CC];
    __shared__ float b2s[CC];
    __shared__ float cs[HH];
    __shared__ float d2s[NN];
    __shared__ float accs[8][CC];
    __shared__ int   redc[4 * 2];
    __shared__ float invs[2];

    for (int idx = t; idx < HH * CC; idx += 256) W2s[idx] = W2[idx];
    if (t < CC) b2s[t] = b2[t];
    const float q0 = latq[i * 2 + 0];
    const float q1 = latq[i * 2 + 1];
    if (t < HH) cs[t] = q0 * W1[2 * HH + t] + q1 * W1[3 * HH + t] + b1[t];

    const float t1 = 0.01f;   // (0.1*1)^2 in fp32
    const float t2 = 0.04f;   // (0.1*2)^2 in fp32

    // Pass A: all-pairs squared distance (bit-exact, no fma contraction) + counts
    int c1 = 0, c2 = 0;
    for (int j = t; j < NN; j += 256) {
        float2 xy = ((const float2*)xs)[b * NN + j];
        float dx = __fsub_rn(q0, xy.x);
        float dy = __fsub_rn(q1, xy.y);
        float d2 = __fadd_rn(__fmul_rn(dx, dx), __fmul_rn(dy, dy));
        d2s[j] = d2;
        c1 += (d2 <= t1);
        c2 += (d2 <= t2);
    }
    for (int off = 32; off > 0; off >>= 1) {
        c1 += __shfl_down(c1, off);
        c2 += __shfl_down(c2, off);
    }
    const int wave = t >> 6;
    if ((t & 63) == 0) { redc[wave * 2] = c1; redc[wave * 2 + 1] = c2; }
    __syncthreads();
    if (t == 0) {
        int s1 = redc[0] + redc[2] + redc[4] + redc[6];
        int s2 = redc[1] + redc[3] + redc[5] + redc[7];
        invs[0] = 1.0f / fmaxf((float)s1, 1.0f);
        invs[1] = 1.0f / fmaxf((float)s2, 1.0f);
    }
    __syncthreads();
    const float inv1 = invs[0], inv2 = invs[1];

    // Pass B: sparse neighbor walk. group gid handles j = gid, gid+8, ...
    const int gid = t >> 5;
    const int c = t & 31;
    float acc = 0.0f;
    for (int j = gid; j < NN; j += 8) {
        float d2 = d2s[j];
        if (d2 > t2) continue;
        float w = (d2 <= t1 ? inv1 : 0.0f) + inv2;
        const float* aj = &a[(b * NN + j) * HH];
        // each lane computes one hidden unit, broadcast via shfl within 32-lane group
        float myh = gelu_tanh(aj[c] + cs[c]);
        float kc = b2s[c];
        #pragma unroll
        for (int h = 0; h < HH; ++h) {
            float hv = __shfl(myh, h, 32);
            kc = fmaf(hv, W2s[h * CC + c], kc);
        }
        float fv = f[(b * NN + j) * CC + c];
        acc = fmaf(w, kc * fv, acc);
    }
    accs[gid][c] = acc;
    __syncthreads();
    if (t < CC) {
        float s = 0.0f;
        #pragma unroll
        for (int g = 0; g < 8; ++g) s += accs[g][t];
        out[(b * MM + i) * CC + t] = s;
    }
}

extern "C" void kernel_launch(void* const* d_in, const int* in_sizes, int n_in,
                              void* d_out, int out_size, void* d_ws, size_t ws_size,
                              hipStream_t stream) {
    const float* pndata = (const float*)d_in[0];   // [B,N,16]
    const float* x_coord = (const float*)d_in[1];  // [B,N,2]
    const float* latq = (const float*)d_in[2];     // [M,2]
    const float* W_lift = (const float*)d_in[3];   // [16,32]
    const float* b_lift = (const float*)d_in[4];   // [32]
    const float* W1 = (const float*)d_in[5];       // [4,32]
    const float* b1 = (const float*)d_in[6];       // [32]
    const float* W2 = (const float*)d_in[7];       // [32,32]
    const float* b2 = (const float*)d_in[8];       // [32]
    float* out = (float*)d_out;                    // [B,M,32]

    float* ws = (float*)d_ws;
    float* xs = ws;                         // B*N*2   = 4096 floats
    float* f  = ws + BB * NN * 2;           // B*N*32  = 65536 floats
    float* a  = f + BB * NN * CC;           // B*N*32  = 65536 floats

    gno_prep<<<BB, 256, 0, stream>>>(pndata, x_coord, W_lift, b_lift, W1, xs, f, a);
    gno_main<<<BB * MM, 256, 0, stream>>>(latq, W1, b1, W2, b2, xs, f, a, out);
}

// Round 2
// 20.891 us; speedup vs baseline: 3.7391x; 3.7391x over previous
//
#include <hip/hip_runtime.h>

#define BB 2
#define NN 1024
#define MM 1024
#define DIN 16
#define CC 32
#define HH 32

// jax.nn.gelu default (approximate=True): 0.5*v*(1+tanh(sqrt(2/pi)*(v+0.044715 v^3)))
__device__ __forceinline__ float gelu_tanh(float v) {
    float v3 = v * v * v;
    float u = 0.7978845608028654f * (v + 0.044715f * v3);
    float e = __expf(2.0f * u);          // e^(2u)
    float t = 1.0f - 2.0f / (e + 1.0f);  // tanh(u); e=inf -> 1, e=0 -> -1
    return 0.5f * v * (1.0f + t);
}

// One block per (batch b, query i). 256 threads = 8 groups x 32 channels.
// Fully fused: per-block min/max + rescale + d2 + neighbor compaction +
// kernel-MLP + lifting, no workspace.
__global__ __launch_bounds__(256) void gno_fused(
    const float* __restrict__ pndata, const float* __restrict__ x_coord,
    const float* __restrict__ latq,
    const float* __restrict__ W_lift, const float* __restrict__ b_lift,
    const float* __restrict__ W1, const float* __restrict__ b1,
    const float* __restrict__ W2, const float* __restrict__ b2,
    float* __restrict__ out)
{
    const int bid = blockIdx.x;
    const int b = bid >> 10;           // M = 1024
    const int i = bid & 1023;
    const int t = threadIdx.x;
    const int lane = t & 63;
    const int wave = t >> 6;
    const int g = t >> 5;              // group 0..7
    const int c = t & 31;              // channel 0..31

    __shared__ float2 nbr_xy[NN];          // rescaled coords of neighbors (worst-case N)
    __shared__ unsigned nbr_meta[NN];      // j | (inner<<10)
    __shared__ __align__(16) float hbuf[8 * HH];
    __shared__ float accs[8 * CC];
    __shared__ float redf[4 * 4];
    __shared__ int wcnt[4];
    __shared__ int c1tot;
    __shared__ float invs[2];

    const float2* xcb = (const float2*)x_coord + b * NN;

    // ---- per-block min/max over N (x_coord is tiny & L2-resident) ----
    float mn0 = 1e30f, mx0 = -1e30f, mn1 = 1e30f, mx1 = -1e30f;
    float2 xyc[4];
    #pragma unroll
    for (int kk = 0; kk < 4; ++kk) {
        xyc[kk] = xcb[kk * 256 + t];
        mn0 = fminf(mn0, xyc[kk].x); mx0 = fmaxf(mx0, xyc[kk].x);
        mn1 = fminf(mn1, xyc[kk].y); mx1 = fmaxf(mx1, xyc[kk].y);
    }
    #pragma unroll
    for (int off = 32; off > 0; off >>= 1) {
        mn0 = fminf(mn0, __shfl_down(mn0, off));
        mx0 = fmaxf(mx0, __shfl_down(mx0, off));
        mn1 = fminf(mn1, __shfl_down(mn1, off));
        mx1 = fmaxf(mx1, __shfl_down(mx1, off));
    }
    if (lane == 0) {
        redf[wave * 4 + 0] = mn0; redf[wave * 4 + 1] = mx0;
        redf[wave * 4 + 2] = mn1; redf[wave * 4 + 3] = mx1;
    }
    if (t == 0) c1tot = 0;
    __syncthreads();
    const float Amn0 = fminf(fminf(redf[0], redf[4]),  fminf(redf[8],  redf[12]));
    const float Amx0 = fmaxf(fmaxf(redf[1], redf[5]),  fmaxf(redf[9],  redf[13]));
    const float Amn1 = fminf(fminf(redf[2], redf[6]),  fminf(redf[10], redf[14]));
    const float Amx1 = fmaxf(fmaxf(redf[3], redf[7]),  fmaxf(redf[11], redf[15]));
    // denom = (mx - mn) + 1e-12, each op rounded separately (matches numpy)
    const float den0 = __fadd_rn(__fsub_rn(Amx0, Amn0), 1e-12f);
    const float den1 = __fadd_rn(__fsub_rn(Amx1, Amn1), 1e-12f);

    const float q0 = latq[2 * i];
    const float q1 = latq[2 * i + 1];
    const float t1 = 0.01f;   // (0.1*1)^2
    const float t2 = 0.04f;   // (0.1*2)^2

    // ---- Pass A: d2 + deterministic ballot/prefix neighbor compaction ----
    int rt = 0;  // running total of compacted neighbors
    #pragma unroll
    for (int kk = 0; kk < 4; ++kk) {
        const int j = kk * 256 + t;
        // rescale: 2*(x-mn)/den - 1, no contraction (bit-exact vs numpy)
        float r0 = __fsub_rn(__fdiv_rn(__fmul_rn(2.0f, __fsub_rn(xyc[kk].x, Amn0)), den0), 1.0f);
        float r1 = __fsub_rn(__fdiv_rn(__fmul_rn(2.0f, __fsub_rn(xyc[kk].y, Amn1)), den1), 1.0f);
        float dx = __fsub_rn(q0, r0);
        float dy = __fsub_rn(q1, r1);
        float d2 = __fadd_rn(__fmul_rn(dx, dx), __fmul_rn(dy, dy));
        bool h2 = d2 <= t2;
        bool h1 = d2 <= t1;
        unsigned long long m2 = __ballot(h2);
        unsigned long long m1 = __ballot(h1);
        int pos = __popcll(m2 & ((1ull << lane) - 1ull));
        if (lane == 0) {
            wcnt[wave] = (int)__popcll(m2);
            atomicAdd(&c1tot, (int)__popcll(m1));   // int adds: order-independent
        }
        __syncthreads();
        int base = rt;
        for (int w = 0; w < wave; ++w) base += wcnt[w];
        if (h2) {
            int idx = base + pos;
            nbr_meta[idx] = (unsigned)j | (h1 ? 1024u : 0u);
            nbr_xy[idx] = make_float2(r0, r1);
        }
        rt += wcnt[0] + wcnt[1] + wcnt[2] + wcnt[3];
        __syncthreads();
    }
    const int K2 = rt;

    if (t == 0) {
        invs[0] = 1.0f / fmaxf((float)c1tot, 1.0f);
        invs[1] = 1.0f / fmaxf((float)K2, 1.0f);
    }

    // per-lane weight columns (loaded after Pass A to shorten live ranges)
    const float w1a = W1[c];
    const float w1b = W1[HH + c];
    const float w1c = W1[2 * HH + c];
    const float w1d = W1[3 * HH + c];
    const float b1v = b1[c];
    const float b2v = b2[c];
    const float blv = b_lift[c];
    float wl[DIN];
    #pragma unroll
    for (int k = 0; k < DIN; ++k) wl[k] = W_lift[k * CC + c];
    float w2c[HH];
    #pragma unroll
    for (int h = 0; h < HH; ++h) w2c[h] = W2[h * CC + c];

    __syncthreads();
    const float inv1 = invs[0], inv2 = invs[1];
    const float ci = fmaf(q1, w1d, fmaf(q0, w1c, b1v));

    // ---- Pass B: walk compact neighbor list, uniform trip count ----
    float acc = 0.0f;
    const int nt = (K2 + 7) >> 3;
    for (int it = 0; it < nt; ++it) {
        const int ib = it * 8 + g;
        const bool active = ib < K2;
        const int ibs = active ? ib : 0;         // K2 > 0 here
        const unsigned meta = nbr_meta[ibs];
        const float2 xy = nbr_xy[ibs];
        const int j = (int)(meta & 1023u);
        const float w = ((meta & 1024u) ? inv1 : 0.0f) + inv2;

        // hidden unit h=c for this neighbor, share via LDS (same wave, no barrier)
        float pre = fmaf(xy.y, w1b, fmaf(xy.x, w1a, ci));
        hbuf[g * HH + c] = gelu_tanh(pre);

        float kc = b2v;
        const float4* hb4 = (const float4*)&hbuf[g * HH];
        #pragma unroll
        for (int hh = 0; hh < 8; ++hh) {
            float4 hv = hb4[hh];                 // broadcast read within group
            kc = fmaf(hv.x, w2c[4 * hh + 0], kc);
            kc = fmaf(hv.y, w2c[4 * hh + 1], kc);
            kc = fmaf(hv.z, w2c[4 * hh + 2], kc);
            kc = fmaf(hv.w, w2c[4 * hh + 3], kc);
        }

        // lifting f[j][c] on the fly (pndata reads broadcast within group, L2-hot)
        const float4* pd4 = (const float4*)&pndata[(b * NN + j) * DIN];
        float fv = blv;
        #pragma unroll
        for (int k4 = 0; k4 < 4; ++k4) {
            float4 p = pd4[k4];
            fv = fmaf(p.x, wl[4 * k4 + 0], fv);
            fv = fmaf(p.y, wl[4 * k4 + 1], fv);
            fv = fmaf(p.z, wl[4 * k4 + 2], fv);
            fv = fmaf(p.w, wl[4 * k4 + 3], fv);
        }

        if (active) acc = fmaf(w, kc * fv, acc);
    }
    accs[g * CC + c] = acc;
    __syncthreads();
    if (t < CC) {
        float s = 0.0f;
        #pragma unroll
        for (int g2 = 0; g2 < 8; ++g2) s += accs[g2 * CC + t];
        out[(b * MM + i) * CC + t] = s;
    }
}

extern "C" void kernel_launch(void* const* d_in, const int* in_sizes, int n_in,
                              void* d_out, int out_size, void* d_ws, size_t ws_size,
                              hipStream_t stream) {
    const float* pndata = (const float*)d_in[0];   // [B,N,16]
    const float* x_coord = (const float*)d_in[1];  // [B,N,2]
    const float* latq = (const float*)d_in[2];     // [M,2]
    const float* W_lift = (const float*)d_in[3];   // [16,32]
    const float* b_lift = (const float*)d_in[4];   // [32]
    const float* W1 = (const float*)d_in[5];       // [4,32]
    const float* b1 = (const float*)d_in[6];       // [32]
    const float* W2 = (const float*)d_in[7];       // [32,32]
    const float* b2 = (const float*)d_in[8];       // [32]
    float* out = (float*)d_out;                    // [B,M,32]

    gno_fused<<<BB * MM, 256, 0, stream>>>(pndata, x_coord, latq,
                                           W_lift, b_lift, W1, b1, W2, b2, out);
}

// Round 3
// 20.012 us; speedup vs baseline: 3.9033x; 1.0439x over previous
//
#include <hip/hip_runtime.h>

#define BB 2
#define NN 1024
#define MM 1024
#define DIN 16
#define CC 32
#define HH 32

// jax.nn.gelu default (approximate=True): 0.5*v*(1+tanh(sqrt(2/pi)*(v+0.044715 v^3)))
__device__ __forceinline__ float gelu_tanh(float v) {
    float v3 = v * v * v;
    float u = 0.7978845608028654f * (v + 0.044715f * v3);
    float e = __expf(2.0f * u);          // e^(2u)
    float t = 1.0f - 2.0f / (e + 1.0f);  // tanh(u); e=inf -> 1, e=0 -> -1
    return 0.5f * v * (1.0f + t);
}

// One block per (batch b, query i). 256 threads = 4 waves; 8 groups x 32 channels.
// Wave-local neighbor compaction: only 3 __syncthreads in the whole kernel.
__global__ __launch_bounds__(256) void gno_fused(
    const float* __restrict__ pndata, const float* __restrict__ x_coord,
    const float* __restrict__ latq,
    const float* __restrict__ W_lift, const float* __restrict__ b_lift,
    const float* __restrict__ W1, const float* __restrict__ b1,
    const float* __restrict__ W2, const float* __restrict__ b2,
    float* __restrict__ out)
{
    const int bid = blockIdx.x;
    const int b = bid >> 10;           // M = 1024
    const int i = bid & 1023;
    const int t = threadIdx.x;
    const int lane = t & 63;
    const int wave = t >> 6;
    const int g = t >> 5;              // group 0..7
    const int c = t & 31;              // channel 0..31

    __shared__ float2 nbr_xy[NN];          // per-wave segments of 256
    __shared__ unsigned nbr_meta[NN];      // j | (inner<<10)
    __shared__ __align__(16) float hbuf[8 * HH];
    __shared__ float accs[8 * CC];
    __shared__ float redf[4 * 4];
    __shared__ int kcnt[4];
    __shared__ int k1cnt[4];

    // ---- issue per-lane weight-column loads early (independent of everything) ----
    const float w1a = W1[c];
    const float w1b = W1[HH + c];
    const float w1c = W1[2 * HH + c];
    const float w1d = W1[3 * HH + c];
    const float b1v = b1[c];
    const float b2v = b2[c];
    const float blv = b_lift[c];
    float wl[DIN];
    #pragma unroll
    for (int k = 0; k < DIN; ++k) wl[k] = W_lift[k * CC + c];
    float w2c[HH];
    #pragma unroll
    for (int h = 0; h < HH; ++h) w2c[h] = W2[h * CC + c];

    const float q0 = latq[2 * i];
    const float q1 = latq[2 * i + 1];

    // ---- per-block min/max over N; wave w loads its own 256 points ----
    const float2* xcb = (const float2*)x_coord + b * NN;
    float2 xyc[4];
    float mn0 = 1e30f, mx0 = -1e30f, mn1 = 1e30f, mx1 = -1e30f;
    #pragma unroll
    for (int kk = 0; kk < 4; ++kk) {
        xyc[kk] = xcb[wave * 256 + kk * 64 + lane];
        mn0 = fminf(mn0, xyc[kk].x); mx0 = fmaxf(mx0, xyc[kk].x);
        mn1 = fminf(mn1, xyc[kk].y); mx1 = fmaxf(mx1, xyc[kk].y);
    }
    #pragma unroll
    for (int off = 32; off > 0; off >>= 1) {
        mn0 = fminf(mn0, __shfl_down(mn0, off));
        mx0 = fmaxf(mx0, __shfl_down(mx0, off));
        mn1 = fminf(mn1, __shfl_down(mn1, off));
        mx1 = fmaxf(mx1, __shfl_down(mx1, off));
    }
    if (lane == 0) {
        redf[wave * 4 + 0] = mn0; redf[wave * 4 + 1] = mx0;
        redf[wave * 4 + 2] = mn1; redf[wave * 4 + 3] = mx1;
    }
    __syncthreads();                                          // barrier 1
    const float Amn0 = fminf(fminf(redf[0], redf[4]),  fminf(redf[8],  redf[12]));
    const float Amx0 = fmaxf(fmaxf(redf[1], redf[5]),  fmaxf(redf[9],  redf[13]));
    const float Amn1 = fminf(fminf(redf[2], redf[6]),  fminf(redf[10], redf[14]));
    const float Amx1 = fmaxf(fmaxf(redf[3], redf[7]),  fmaxf(redf[11], redf[15]));
    // denom = (mx - mn) + 1e-12, each op rounded separately (matches numpy)
    const float den0 = __fadd_rn(__fsub_rn(Amx0, Amn0), 1e-12f);
    const float den1 = __fadd_rn(__fsub_rn(Amx1, Amn1), 1e-12f);

    const float t1 = 0.01f;   // (0.1*1)^2
    const float t2 = 0.04f;   // (0.1*2)^2

    // ---- Pass A: wave-local d2 + ballot compaction into segment [wave*256, ...) ----
    const unsigned long long lmask = (1ull << lane) - 1ull;
    int kw = 0, k1w = 0;
    #pragma unroll
    for (int kk = 0; kk < 4; ++kk) {
        const int j = wave * 256 + kk * 64 + lane;
        float r0 = __fsub_rn(__fdiv_rn(__fmul_rn(2.0f, __fsub_rn(xyc[kk].x, Amn0)), den0), 1.0f);
        float r1 = __fsub_rn(__fdiv_rn(__fmul_rn(2.0f, __fsub_rn(xyc[kk].y, Amn1)), den1), 1.0f);
        float dx = __fsub_rn(q0, r0);
        float dy = __fsub_rn(q1, r1);
        float d2 = __fadd_rn(__fmul_rn(dx, dx), __fmul_rn(dy, dy));
        bool h2 = d2 <= t2;
        bool h1 = d2 <= t1;
        unsigned long long m2 = __ballot(h2);
        unsigned long long m1 = __ballot(h1);
        if (h2) {
            int idx = wave * 256 + kw + __popcll(m2 & lmask);
            nbr_meta[idx] = (unsigned)j | (h1 ? 1024u : 0u);
            nbr_xy[idx] = make_float2(r0, r1);
        }
        kw += (int)__popcll(m2);
        k1w += (int)__popcll(m1);
    }
    if (lane == 0) { kcnt[wave] = kw; k1cnt[wave] = k1w; }
    __syncthreads();                                          // barrier 2

    const int Ks0 = kcnt[0], Ks1 = kcnt[1], Ks2 = kcnt[2], Ks3 = kcnt[3];
    const int K2 = Ks0 + Ks1 + Ks2 + Ks3;
    const int c1 = k1cnt[0] + k1cnt[1] + k1cnt[2] + k1cnt[3];
    const float inv1 = 1.0f / fmaxf((float)c1, 1.0f);   // exact div, identical all lanes
    const float inv2 = 1.0f / fmaxf((float)K2, 1.0f);
    const float ci = fmaf(q1, w1d, fmaf(q0, w1c, b1v));

    // ---- Pass B: walk the 4 compact segments (uniform control flow per group) ----
    float acc = 0.0f;
    #pragma unroll
    for (int seg = 0; seg < 4; ++seg) {
        const int Ks = (seg == 0) ? Ks0 : (seg == 1) ? Ks1 : (seg == 2) ? Ks2 : Ks3;
        const int base = seg * 256;
        const int nt = (Ks + 7) >> 3;
        for (int it = 0; it < nt; ++it) {
            const int ib = it * 8 + g;
            const bool active = ib < Ks;
            const int idx = base + (active ? ib : 0);
            const unsigned meta = nbr_meta[idx];
            const float2 xy = nbr_xy[idx];
            const int j = (int)(meta & 1023u);
            const float w = ((meta & 1024u) ? inv1 : 0.0f) + inv2;

            // hidden unit h=c for this neighbor; share within group via LDS (same wave)
            float pre = fmaf(xy.y, w1b, fmaf(xy.x, w1a, ci));
            hbuf[g * HH + c] = gelu_tanh(pre);

            float kc = b2v;
            const float4* hb4 = (const float4*)&hbuf[g * HH];
            #pragma unroll
            for (int hh = 0; hh < 8; ++hh) {
                float4 hv = hb4[hh];             // broadcast read within group
                kc = fmaf(hv.x, w2c[4 * hh + 0], kc);
                kc = fmaf(hv.y, w2c[4 * hh + 1], kc);
                kc = fmaf(hv.z, w2c[4 * hh + 2], kc);
                kc = fmaf(hv.w, w2c[4 * hh + 3], kc);
            }

            // lifting f[j][c] on the fly (broadcast reads within group, L2-hot)
            const float4* pd4 = (const float4*)&pndata[(b * NN + j) * DIN];
            float fv = blv;
            #pragma unroll
            for (int k4 = 0; k4 < 4; ++k4) {
                float4 p = pd4[k4];
                fv = fmaf(p.x, wl[4 * k4 + 0], fv);
                fv = fmaf(p.y, wl[4 * k4 + 1], fv);
                fv = fmaf(p.z, wl[4 * k4 + 2], fv);
                fv = fmaf(p.w, wl[4 * k4 + 3], fv);
            }

            if (active) acc = fmaf(w, kc * fv, acc);
        }
    }
    accs[g * CC + c] = acc;
    __syncthreads();                                          // barrier 3
    if (t < CC) {
        float s = 0.0f;
        #pragma unroll
        for (int g2 = 0; g2 < 8; ++g2) s += accs[g2 * CC + t];
        out[(b * MM + i) * CC + t] = s;
    }
}

extern "C" void kernel_launch(void* const* d_in, const int* in_sizes, int n_in,
                              void* d_out, int out_size, void* d_ws, size_t ws_size,
                              hipStream_t stream) {
    const float* pndata = (const float*)d_in[0];   // [B,N,16]
    const float* x_coord = (const float*)d_in[1];  // [B,N,2]
    const float* latq = (const float*)d_in[2];     // [M,2]
    const float* W_lift = (const float*)d_in[3];   // [16,32]
    const float* b_lift = (const float*)d_in[4];   // [32]
    const float* W1 = (const float*)d_in[5];       // [4,32]
    const float* b1 = (const float*)d_in[6];       // [32]
    const float* W2 = (const float*)d_in[7];       // [32,32]
    const float* b2 = (const float*)d_in[8];       // [32]
    float* out = (float*)d_out;                    // [B,M,32]

    gno_fused<<<BB * MM, 256, 0, stream>>>(pndata, x_coord, latq,
                                           W_lift, b_lift, W1, b1, W2, b2, out);
}